// Round 12
// baseline (243.782 us; speedup 1.0000x reference)
//
#include <hip/hip_runtime.h>
#include <math.h>

// Problem constants
#define BATCH   16
#define CDIM    512
#define HWDIM   9216      // 96*96
#define NCLS    64
#define TILE    128
#define NTILES  72        // 9216/128
#define NCHUNK  16        // 512/32

// Output layout (floats): heatmap[16*9216], logits[16], loss[1], ip[16*64*9216]
#define LOGOFF  147456
#define LOSSOFF 147472
#define IPOFF   147473

// Workspace layout (floats)
#define WS_S    65536     // s[64]
#define WS_PH   65600     // per-block heat sums [1152]
#define WS_PC   66752     // per-block cluster sums [1152]
#define WS_AP   67904     // A fragments: 16 chunks * 3p * (2s*4mt) * 64lane * 4 floats

typedef __attribute__((ext_vector_type(8))) short bf16x8;
typedef __attribute__((ext_vector_type(16))) float f32x16;

__device__ __forceinline__ void split3(float v, float& h, float& m, float& l) {
  float hf = __uint_as_float(__float_as_uint(v) & 0xFFFF0000u);
  float r  = v - hf;                    // exact
  float mf = __uint_as_float(__float_as_uint(r) & 0xFFFF0000u);
  float r2 = r - mf;                    // exact
  float lf = __uint_as_float(__float_as_uint(r2) & 0xFFFF0000u);
  h = hf; m = mf; l = lf;
}

__device__ __forceinline__ unsigned packbf(float a, float b) {
  return (__float_as_uint(a) >> 16) | (__float_as_uint(b) & 0xFFFF0000u);
}

// ---------------------------------------------------------------------------
// prep: block n (64 blocks) computes mix row n, s[n], new_centers row 64+n,
// and packs fragment rows for the 32x32x16 MFMA layout:
//   fragment (chunk c, piece p, s, mtile, lane): row = mtile*32 + (lane&31),
//   k = c*32 + s*16 + (lane>>5)*8 + e.   mtiles 0,1 = centers; 2,3 = new.
// float offset: WS_AP + c*6144 + p*2048 + (s*4+mt)*256 + lane*4
// ---------------------------------------------------------------------------
__global__ __launch_bounds__(256) void prep_kernel(
    const float* __restrict__ centers, const float* __restrict__ Aadj,
    const float* __restrict__ W_bc, const float* __restrict__ b_bc,
    const float* __restrict__ W_gcn, const float* __restrict__ b_gcn,
    float* __restrict__ ws) {
  __shared__ float c_row[CDIM];
  __shared__ float mix_row[CDIM];
  __shared__ float new_row[CDIM];
  __shared__ float a_n[NCLS];
  __shared__ float red[256];
  const int n = blockIdx.x;
  const int tid = threadIdx.x;

  if (tid < NCLS) a_n[tid] = Aadj[n * NCLS + tid] + (tid == n ? 1.0f : 0.0f);
  __syncthreads();
  if (tid == 0) {
    float ssum = 0.f;
    for (int w = 0; w < NCLS; ++w) ssum += a_n[w];
    red[0] = 1.0f / ssum;
  }
  __syncthreads();
  float inv = red[0];
  __syncthreads();
  if (tid < NCLS) a_n[tid] *= inv;
  __syncthreads();

  float p = 0.f;
  for (int c = tid; c < CDIM; c += 256) {
    float v = centers[n * CDIM + c];
    c_row[c] = v;
    float acc = 0.f;
    #pragma unroll 8
    for (int w = 0; w < NCLS; ++w) acc = fmaf(a_n[w], centers[w * CDIM + c], acc);
    mix_row[c] = 0.05f * v + 0.95f * acc;
    p = fmaf(W_bc[c], v, p);
  }
  red[tid] = p;
  __syncthreads();
  for (int st = 128; st > 0; st >>= 1) {
    if (tid < st) red[tid] += red[tid + st];
    __syncthreads();
  }
  if (tid == 0) ws[WS_S + n] = red[0] + b_bc[0];
  __syncthreads();

  for (int o = tid; o < CDIM; o += 256) {
    const float4* wr0 = (const float4*)(W_gcn + (size_t)o * 1024);
    const float4* wr1 = (const float4*)(W_gcn + (size_t)o * 1024 + 512);
    const float4* cr4 = (const float4*)c_row;
    const float4* mr4 = (const float4*)mix_row;
    float a0 = b_gcn[o], a1 = 0.f, a2 = 0.f, a3 = 0.f;
    #pragma unroll 4
    for (int qk = 0; qk < 128; ++qk) {
      float4 wv = wr0[qk], cv = cr4[qk];
      a0 = fmaf(wv.x, cv.x, a0);
      a1 = fmaf(wv.y, cv.y, a1);
      a2 = fmaf(wv.z, cv.z, a2);
      a3 = fmaf(wv.w, cv.w, a3);
    }
    #pragma unroll 4
    for (int qk = 0; qk < 128; ++qk) {
      float4 wv = wr1[qk], mv = mr4[qk];
      a0 = fmaf(wv.x, mv.x, a0);
      a1 = fmaf(wv.y, mv.y, a1);
      a2 = fmaf(wv.z, mv.z, a2);
      a3 = fmaf(wv.w, mv.w, a3);
    }
    new_row[o] = (a0 + a1) + (a2 + a3);
  }
  __syncthreads();

  // pack: 128 threads, each handles (rowsel, chunk c, s, hh) -> 3 uint4
  if (tid < 128) {
    const int rowsel = tid >> 6;          // 0: centers row n, 1: new row 64+n
    const int u = tid & 63;
    const int c = u >> 2;                 // chunk
    const int s = (u >> 1) & 1;
    const int hh = u & 1;
    const float* rbuf = rowsel ? new_row : c_row;
    const int mt = (rowsel ? 2 : 0) + (n >> 5);
    const int lane = (n & 31) + 32 * hh;
    float e[8];
    #pragma unroll
    for (int i = 0; i < 8; ++i) e[i] = rbuf[c * 32 + s * 16 + hh * 8 + i];
    unsigned dh[4], dm[4], dl[4];
    #pragma unroll
    for (int d = 0; d < 4; ++d) {
      float h0, m0, l0, h1, m1, l1;
      split3(e[2 * d], h0, m0, l0);
      split3(e[2 * d + 1], h1, m1, l1);
      dh[d] = packbf(h0, h1); dm[d] = packbf(m0, m1); dl[d] = packbf(l0, l1);
    }
    float* dst = ws + WS_AP + (size_t)c * 6144 + (size_t)(s * 4 + mt) * 256 + (size_t)lane * 4;
    *(uint4*)(dst)        = make_uint4(dh[0], dh[1], dh[2], dh[3]);
    *(uint4*)(dst + 2048) = make_uint4(dm[0], dm[1], dm[2], dm[3]);
    *(uint4*)(dst + 4096) = make_uint4(dl[0], dl[1], dl[2], dl[3]);
  }
}

// ---------------------------------------------------------------------------
// Main: MFMA 32x32x16 split-bf16 dual GEMM. Wave w: mhalf=w&1, nhalf=w>>1.
// B reg-staged 1-chunk lead into double-buffered LDS (fragment units of 1KB:
// byte off = p*8192 + (s*4+n)*1024 + lane*16). A reg-prefetched 1 chunk ahead.
// ---------------------------------------------------------------------------
__global__ __launch_bounds__(256, 3) void main_kernel(
    const float* __restrict__ x, const float* __restrict__ gumbel,
    float* __restrict__ ws, float* __restrict__ out) {
  __shared__ char ldsmem[49152];          // 2 x 24576 B buffers
  __shared__ float s_sh[NCLS];
  char* buf0 = ldsmem;
  char* buf1 = ldsmem + 24576;

  const int tid = threadIdx.x;
  const int w = tid >> 6, l = tid & 63;
  const int mh = w & 1, nh = w >> 1;
  const int h = l >> 5, c31 = l & 31;
  const int tile = blockIdx.x, b = blockIdx.y;
  const int hw0 = tile * TILE;

  if (tid < NCLS) s_sh[tid] = ws[WS_S + tid];

  const float* xb = x + (size_t)b * CDIM * HWDIM;
  // producer: thread stages fragment slots (s=0,1, n=w, lane=l):
  // col = hw0 + w*32 + c31, k = c*32 + s*16 + h*8 + e
  const float* pB = xb + (size_t)(h * 8) * HWDIM + hw0 + w * 32 + c31;
  const char* ap = (const char*)(ws + WS_AP);
  const int la16 = l * 16;

  f32x16 cip[2], cnp[2];
  #pragma unroll
  for (int i = 0; i < 2; ++i) {
    cip[i] = (f32x16)(0.f);
    cnp[i] = (f32x16)(0.f);
  }

  float bre[16];
  bf16x8 A0[10], A1[10];

// A slots for this wave: s=0: [0]=aH,[1]=aM,[2]=aL,[3]=nH,[4]=nM ; s=1: [5..9]
#define LOAD_A(AS, c_) do {                                                   \
    const char* asrc = ap + (size_t)(c_) * 24576;                             \
    AS[0] = *(const bf16x8*)(asrc + (0 + mh) * 1024 + la16);                  \
    AS[1] = *(const bf16x8*)(asrc + 8192 + (0 + mh) * 1024 + la16);           \
    AS[2] = *(const bf16x8*)(asrc + 16384 + (0 + mh) * 1024 + la16);          \
    AS[3] = *(const bf16x8*)(asrc + (2 + mh) * 1024 + la16);                  \
    AS[4] = *(const bf16x8*)(asrc + 8192 + (2 + mh) * 1024 + la16);           \
    AS[5] = *(const bf16x8*)(asrc + (4 + mh) * 1024 + la16);                  \
    AS[6] = *(const bf16x8*)(asrc + 8192 + (4 + mh) * 1024 + la16);          \
    AS[7] = *(const bf16x8*)(asrc + 16384 + (4 + mh) * 1024 + la16);         \
    AS[8] = *(const bf16x8*)(asrc + (6 + mh) * 1024 + la16);                  \
    AS[9] = *(const bf16x8*)(asrc + 8192 + (6 + mh) * 1024 + la16);          \
  } while (0)

#define LOAD_B(c_) do {                                                       \
    const size_t koff = (size_t)(c_) * 32 * HWDIM;                            \
    _Pragma("unroll")                                                         \
    for (int e = 0; e < 8; ++e) {                                             \
      bre[e]     = pB[koff + (size_t)e * HWDIM];                              \
      bre[8 + e] = pB[koff + (size_t)(16 + e) * HWDIM];                       \
    }                                                                         \
  } while (0)

#define WRITE_B(WB) do {                                                      \
    _Pragma("unroll")                                                         \
    for (int s = 0; s < 2; ++s) {                                             \
      unsigned dh[4], dm[4], dl[4];                                           \
      _Pragma("unroll")                                                       \
      for (int d = 0; d < 4; ++d) {                                           \
        float h0, m0, l0, h1, m1, l1;                                         \
        split3(bre[s * 8 + 2 * d], h0, m0, l0);                               \
        split3(bre[s * 8 + 2 * d + 1], h1, m1, l1);                           \
        dh[d] = packbf(h0, h1); dm[d] = packbf(m0, m1); dl[d] = packbf(l0, l1);\
      }                                                                       \
      char* basep = (WB) + (s * 4 + w) * 1024 + la16;                         \
      *(uint4*)(basep)         = make_uint4(dh[0], dh[1], dh[2], dh[3]);      \
      *(uint4*)(basep + 8192)  = make_uint4(dm[0], dm[1], dm[2], dm[3]);      \
      *(uint4*)(basep + 16384) = make_uint4(dl[0], dl[1], dl[2], dl[3]);      \
    }                                                                         \
  } while (0)

#define MFMA32 __builtin_amdgcn_mfma_f32_32x32x16_bf16

#define PHASE_S(RB, AC, S, OFF) do {                                          \
    _Pragma("unroll")                                                         \
    for (int nt = 0; nt < 2; ++nt) {                                          \
      const int nn = nh * 2 + nt;                                             \
      bf16x8 bH = *(const bf16x8*)((RB) + ((S) * 4 + nn) * 1024 + la16);      \
      bf16x8 bM = *(const bf16x8*)((RB) + 8192 + ((S) * 4 + nn) * 1024 + la16); \
      bf16x8 bL = *(const bf16x8*)((RB) + 16384 + ((S) * 4 + nn) * 1024 + la16); \
      cip[nt] = MFMA32(AC[OFF + 0], bH, cip[nt], 0, 0, 0);                    \
      cip[nt] = MFMA32(AC[OFF + 0], bM, cip[nt], 0, 0, 0);                    \
      cip[nt] = MFMA32(AC[OFF + 1], bH, cip[nt], 0, 0, 0);                    \
      cip[nt] = MFMA32(AC[OFF + 0], bL, cip[nt], 0, 0, 0);                    \
      cip[nt] = MFMA32(AC[OFF + 1], bM, cip[nt], 0, 0, 0);                    \
      cip[nt] = MFMA32(AC[OFF + 2], bH, cip[nt], 0, 0, 0);                    \
      cnp[nt] = MFMA32(AC[OFF + 3], bH, cnp[nt], 0, 0, 0);                    \
      cnp[nt] = MFMA32(AC[OFF + 3], bM, cnp[nt], 0, 0, 0);                    \
      cnp[nt] = MFMA32(AC[OFF + 4], bH, cnp[nt], 0, 0, 0);                    \
    }                                                                         \
  } while (0)

#define CHUNK(c_, RB, WB, AC, AN) do {                                        \
    if ((c_) + 1 < NCHUNK) { LOAD_A(AN, (c_) + 1); LOAD_B((c_) + 1); }        \
    PHASE_S(RB, AC, 0, 0);                                                    \
    PHASE_S(RB, AC, 1, 5);                                                    \
    if ((c_) + 1 < NCHUNK) WRITE_B(WB);                                       \
    __syncthreads();                                                          \
  } while (0)

  // prologue: chunk 0 staged into buf0
  LOAD_A(A0, 0);
  LOAD_B(0);
  WRITE_B(buf0);
  __syncthreads();

  #pragma unroll 1
  for (int cc = 0; cc < NCHUNK; cc += 2) {
    CHUNK(cc, buf0, buf1, A0, A1);
    CHUNK(cc + 1, buf1, buf0, A1, A0);
  }

  // ---------------- epilogue ----------------
  float* pvv  = (float*)ldsmem;             // [2][128]
  int*   pvi  = (int*)(ldsmem + 1024);      // [2][128]
  float* pnm  = (float*)(ldsmem + 2048);    // [2][128]
  float* pns  = (float*)(ldsmem + 3072);    // [2][128]
  float* m2   = (float*)(ldsmem + 4096);    // [128]
  float* hbuf = (float*)(ldsmem + 4608);    // [128]
  float* cbuf = (float*)(ldsmem + 5120);    // [128]

  const size_t bn = (size_t)b * NCLS;
  float* ipo = out + IPOFF;

  #pragma unroll
  for (int nt = 0; nt < 2; ++nt) {
    const int col = nh * 64 + nt * 32 + c31;
    const int gcol = hw0 + col;
    float best = -1e30f; int bi = 0;
    #pragma unroll
    for (int r = 0; r < 16; ++r) {
      const int nrow = mh * 32 + (r & 3) + 8 * (r >> 2) + 4 * h;
      const size_t off = (bn + nrow) * HWDIM + gcol;
      const float v = cip[nt][r];
      ipo[off] = v;
      const float t = v + gumbel[off];
      if (t > best) { best = t; bi = nrow; }   // rows ascending in r
    }
    {
      float ov = __shfl_xor(best, 32);
      int   oi = __shfl_xor(bi, 32);
      if (ov > best || (ov == best && oi < bi)) { best = ov; bi = oi; }
    }
    float mx = -1e30f;
    #pragma unroll
    for (int r = 0; r < 16; ++r) mx = fmaxf(mx, cnp[nt][r]);
    mx = fmaxf(mx, __shfl_xor(mx, 32));
    if (h == 0) {
      pvv[mh * 128 + col] = best;
      pvi[mh * 128 + col] = bi;
      pnm[mh * 128 + col] = mx;
    }
  }
  __syncthreads();

  if (tid < 128) {
    float v = pvv[tid]; int i = pvi[tid];
    float v2 = pvv[128 + tid]; int i2 = pvi[128 + tid];
    if (v2 > v || (v2 == v && i2 < i)) { v = v2; i = i2; }
    float hh2 = s_sh[i];
    hbuf[tid] = hh2;
    out[(size_t)b * HWDIM + hw0 + tid] = hh2;
    m2[tid] = fmaxf(pnm[tid], pnm[128 + tid]);
  }
  __syncthreads();

  #pragma unroll
  for (int nt = 0; nt < 2; ++nt) {
    const int col = nh * 64 + nt * 32 + c31;
    const float mm = m2[col];
    float se = 0.f;
    #pragma unroll
    for (int r = 0; r < 16; ++r) se += __expf(cnp[nt][r] - mm);
    se += __shfl_xor(se, 32);
    if (h == 0) pns[mh * 128 + col] = se;
  }
  __syncthreads();

  if (tid < 128) {
    float S = pns[tid] + pns[128 + tid];
    cbuf[tid] = 1.0f / S;
  }
  __syncthreads();

  if (tid < 64) {
    float hs = hbuf[tid] + hbuf[tid + 64];
    float cs = cbuf[tid] + cbuf[tid + 64];
    #pragma unroll
    for (int o = 32; o > 0; o >>= 1) {
      hs += __shfl_down(hs, o);
      cs += __shfl_down(cs, o);
    }
    if (tid == 0) {
      ws[WS_PH + b * NTILES + tile] = hs;
      ws[WS_PC + b * NTILES + tile] = cs;
    }
  }
#undef LOAD_A
#undef LOAD_B
#undef WRITE_B
#undef PHASE_S
#undef CHUNK
#undef MFMA32
}

// ---------------------------------------------------------------------------
// Finish: logits + cluster_loss from per-block partials (deterministic order)
// ---------------------------------------------------------------------------
__global__ __launch_bounds__(256) void finish_kernel(
    const float* __restrict__ ws, float* __restrict__ out) {
  __shared__ double sred[256];
  const int tid = threadIdx.x;
  {
    int bb = tid >> 4, lane = tid & 15;
    double s = 0.0;
    for (int t = lane; t < NTILES; t += 16) s += (double)ws[WS_PH + bb * NTILES + t];
    #pragma unroll
    for (int o = 8; o > 0; o >>= 1) s += __shfl_down(s, o, 16);
    if (lane == 0) out[LOGOFF + bb] = (float)(s / (double)HWDIM);
  }
  double c = 0.0;
  for (int i = tid; i < BATCH * NTILES; i += 256) c += (double)ws[WS_PC + i];
  sred[tid] = c;
  __syncthreads();
  for (int st = 128; st > 0; st >>= 1) {
    if (tid < st) sred[tid] += sred[tid + st];
    __syncthreads();
  }
  if (tid == 0) out[LOSSOFF] = (float)(-sred[0] / (double)(BATCH * HWDIM));
}

// ---------------------------------------------------------------------------
extern "C" void kernel_launch(void* const* d_in, const int* in_sizes, int n_in,
                              void* d_out, int out_size, void* d_ws, size_t ws_size,
                              hipStream_t stream) {
  const float* x       = (const float*)d_in[0];
  const float* centers = (const float*)d_in[1];
  const float* Aadj    = (const float*)d_in[2];
  const float* gumbel  = (const float*)d_in[3];
  const float* W_bc    = (const float*)d_in[4];
  const float* b_bc    = (const float*)d_in[5];
  const float* W_gcn   = (const float*)d_in[6];
  const float* b_gcn   = (const float*)d_in[7];
  float* out = (float*)d_out;
  float* ws  = (float*)d_ws;

  hipLaunchKernelGGL(prep_kernel, dim3(NCLS), dim3(256), 0, stream,
                     centers, Aadj, W_bc, b_bc, W_gcn, b_gcn, ws);
  hipLaunchKernelGGL(main_kernel, dim3(NTILES, BATCH), dim3(256), 0, stream,
                     x, gumbel, ws, out);
  hipLaunchKernelGGL(finish_kernel, dim3(1), dim3(256), 0, stream, ws, out);
}

// Round 13
// 186.547 us; speedup vs baseline: 1.3068x; 1.3068x over previous
//
#include <hip/hip_runtime.h>
#include <math.h>

// Problem constants
#define BATCH   16
#define CDIM    512
#define HWDIM   9216      // 96*96
#define NCLS    64
#define TILE    128
#define NTILES  72        // 9216/128
#define NCHUNK  16        // 512/32

// Output layout (floats): heatmap[16*9216], logits[16], loss[1], ip[16*64*9216]
#define LOGOFF  147456
#define LOSSOFF 147472
#define IPOFF   147473

// Workspace layout (floats)
#define WS_S    65536     // s[64]
#define WS_PH   65600     // per-block heat sums [1152]
#define WS_PC   66752     // per-block cluster sums [1152]
#define WS_AP   67904     // A-piece fragments: 16 chunks * 3p * 8mb * 64lane * 4 floats

typedef __attribute__((ext_vector_type(8))) short bf16x8;
typedef __attribute__((ext_vector_type(4))) float f32x4;

__device__ __forceinline__ void split3(float v, float& h, float& m, float& l) {
  float hf = __uint_as_float(__float_as_uint(v) & 0xFFFF0000u);
  float r  = v - hf;                    // exact
  float mf = __uint_as_float(__float_as_uint(r) & 0xFFFF0000u);
  float r2 = r - mf;                    // exact
  float lf = __uint_as_float(__float_as_uint(r2) & 0xFFFF0000u);
  h = hf; m = mf; l = lf;
}

__device__ __forceinline__ void split2(float v, float& h, float& m) {
  float hf = __uint_as_float(__float_as_uint(v) & 0xFFFF0000u);
  float r  = v - hf;                    // exact
  float mf = __uint_as_float(__float_as_uint(r) & 0xFFFF0000u);
  h = hf; m = mf;
}

__device__ __forceinline__ unsigned packbf(float a, float b) {
  return (__float_as_uint(a) >> 16) | (__float_as_uint(b) & 0xFFFF0000u);
}

// ---------------------------------------------------------------------------
// prep: block n (64 blocks) computes mix row n, s[n], new_centers row 64+n,
// and packs fragment rows n (centers) and 64+n (new_centers). (R11 verbatim)
// ---------------------------------------------------------------------------
__global__ __launch_bounds__(256) void prep_kernel(
    const float* __restrict__ centers, const float* __restrict__ Aadj,
    const float* __restrict__ W_bc, const float* __restrict__ b_bc,
    const float* __restrict__ W_gcn, const float* __restrict__ b_gcn,
    float* __restrict__ ws) {
  __shared__ float c_row[CDIM];
  __shared__ float mix_row[CDIM];
  __shared__ float new_row[CDIM];
  __shared__ float a_n[NCLS];
  __shared__ float red[256];
  const int n = blockIdx.x;
  const int tid = threadIdx.x;

  if (tid < NCLS) a_n[tid] = Aadj[n * NCLS + tid] + (tid == n ? 1.0f : 0.0f);
  __syncthreads();
  if (tid == 0) {
    float ssum = 0.f;
    for (int w = 0; w < NCLS; ++w) ssum += a_n[w];
    red[0] = 1.0f / ssum;
  }
  __syncthreads();
  float inv = red[0];
  __syncthreads();
  if (tid < NCLS) a_n[tid] *= inv;
  __syncthreads();

  float p = 0.f;
  for (int c = tid; c < CDIM; c += 256) {
    float v = centers[n * CDIM + c];
    c_row[c] = v;
    float acc = 0.f;
    #pragma unroll 8
    for (int w = 0; w < NCLS; ++w) acc = fmaf(a_n[w], centers[w * CDIM + c], acc);
    mix_row[c] = 0.05f * v + 0.95f * acc;
    p = fmaf(W_bc[c], v, p);
  }
  red[tid] = p;
  __syncthreads();
  for (int st = 128; st > 0; st >>= 1) {
    if (tid < st) red[tid] += red[tid + st];
    __syncthreads();
  }
  if (tid == 0) ws[WS_S + n] = red[0] + b_bc[0];
  __syncthreads();

  for (int o = tid; o < CDIM; o += 256) {
    const float4* wr0 = (const float4*)(W_gcn + (size_t)o * 1024);
    const float4* wr1 = (const float4*)(W_gcn + (size_t)o * 1024 + 512);
    const float4* cr4 = (const float4*)c_row;
    const float4* mr4 = (const float4*)mix_row;
    float a0 = b_gcn[o], a1 = 0.f, a2 = 0.f, a3 = 0.f;
    #pragma unroll 4
    for (int qk = 0; qk < 128; ++qk) {
      float4 wv = wr0[qk], cv = cr4[qk];
      a0 = fmaf(wv.x, cv.x, a0);
      a1 = fmaf(wv.y, cv.y, a1);
      a2 = fmaf(wv.z, cv.z, a2);
      a3 = fmaf(wv.w, cv.w, a3);
    }
    #pragma unroll 4
    for (int qk = 0; qk < 128; ++qk) {
      float4 wv = wr1[qk], mv = mr4[qk];
      a0 = fmaf(wv.x, mv.x, a0);
      a1 = fmaf(wv.y, mv.y, a1);
      a2 = fmaf(wv.z, mv.z, a2);
      a3 = fmaf(wv.w, mv.w, a3);
    }
    new_row[o] = (a0 + a1) + (a2 + a3);
  }
  __syncthreads();

  if (tid < 128) {
    const int rowsel = tid >> 6;          // 0: centers row, 1: new row
    const int u = tid & 63;
    const int c = u >> 2, q = u & 3;
    const float* rbuf = rowsel ? new_row : c_row;
    const int mb = (rowsel ? 4 : 0) + (n >> 4);
    const int lane = q * 16 + (n & 15);
    float e[8];
    #pragma unroll
    for (int i = 0; i < 8; ++i) e[i] = rbuf[c * 32 + q * 8 + i];
    unsigned dh[4], dm[4], dl[4];
    #pragma unroll
    for (int d = 0; d < 4; ++d) {
      float h0, m0, l0, h1, m1, l1;
      split3(e[2 * d], h0, m0, l0);
      split3(e[2 * d + 1], h1, m1, l1);
      dh[d] = packbf(h0, h1); dm[d] = packbf(m0, m1); dl[d] = packbf(l0, l1);
    }
    float* dst = ws + WS_AP + (size_t)c * 6144 + (size_t)mb * 256 + (size_t)lane * 4;
    *(uint4*)(dst)        = make_uint4(dh[0], dh[1], dh[2], dh[3]);
    *(uint4*)(dst + 2048) = make_uint4(dm[0], dm[1], dm[2], dm[3]);
    *(uint4*)(dst + 4096) = make_uint4(dl[0], dl[1], dl[2], dl[3]);
  }
}

// ---------------------------------------------------------------------------
// Main: MFMA split-bf16 dual GEMM (R3/R11 skeleton) with 2-piece B staging:
// ip = aH*bH + aH*bM + aM*bH + aM*bM + aL*bH  (error ~2^-16 rel, negligible)
// nip = nH*bH + nH*bM + nM*bH
// LDS: 2 x 16KB B buffers. A 3-piece, register-prefetched 1 chunk ahead.
// ---------------------------------------------------------------------------
__global__ __launch_bounds__(256, 3) void main_kernel(
    const float* __restrict__ x, const float* __restrict__ gumbel,
    float* __restrict__ ws, float* __restrict__ out) {
  __shared__ char ldsmem[32768];          // 2 x 16384 B-piece buffers
  __shared__ float s_sh[NCLS];
  char* buf0 = ldsmem;
  char* buf1 = ldsmem + 16384;

  const int tid = threadIdx.x;
  const int w = tid >> 6, l = tid & 63;
  const int tile = blockIdx.x, b = blockIdx.y;
  const int hw0 = tile * TILE;

  if (tid < NCLS) s_sh[tid] = ws[WS_S + tid];

  const float* xb = x + (size_t)b * CDIM * HWDIM;
  const float* pB = xb + (size_t)(w * 8) * HWDIM + hw0 + l;   // k = c*32 + w*8 + j
  const char* ap = (const char*)(ws + WS_AP);
  const int la16 = l * 16;

  f32x4 cip[8], cnp[8];
  #pragma unroll
  for (int i = 0; i < 8; ++i) {
    cip[i] = (f32x4){0.f, 0.f, 0.f, 0.f};
    cnp[i] = (f32x4){0.f, 0.f, 0.f, 0.f};
  }

  float bre[16];
  bf16x8 A0[5], A1[5];

#define LOAD_A(AS, c_) do {                                                   \
    const char* asrc = ap + (size_t)(c_) * 24576;                             \
    AS[0] = *(const bf16x8*)(asrc + w * 1024 + la16);                         \
    AS[1] = *(const bf16x8*)(asrc + 8192 + w * 1024 + la16);                  \
    AS[2] = *(const bf16x8*)(asrc + 16384 + w * 1024 + la16);                 \
    AS[3] = *(const bf16x8*)(asrc + (4 + w) * 1024 + la16);                   \
    AS[4] = *(const bf16x8*)(asrc + 8192 + (4 + w) * 1024 + la16);            \
  } while (0)

#define LOAD_B(c_) do {                                                       \
    const size_t koff = (size_t)(c_) * 32 * HWDIM;                            \
    _Pragma("unroll")                                                         \
    for (int j = 0; j < 8; ++j) {                                             \
      bre[j]     = pB[koff + (size_t)j * HWDIM];                              \
      bre[8 + j] = pB[koff + (size_t)j * HWDIM + 64];                         \
    }                                                                         \
  } while (0)

#define WRITE_B(WB) do {                                                      \
    _Pragma("unroll")                                                         \
    for (int hh = 0; hh < 2; ++hh) {                                          \
      unsigned dh[4], dm[4];                                                  \
      _Pragma("unroll")                                                       \
      for (int d = 0; d < 4; ++d) {                                           \
        float h0, m0, h1, m1;                                                 \
        split2(bre[hh * 8 + 2 * d], h0, m0);                                  \
        split2(bre[hh * 8 + 2 * d + 1], h1, m1);                              \
        dh[d] = packbf(h0, h1); dm[d] = packbf(m0, m1);                       \
      }                                                                       \
      char* basep = (WB) + ((((l >> 4) + hh * 4) * 64) + (w << 4) + (l & 15)) * 16; \
      *(uint4*)(basep)        = make_uint4(dh[0], dh[1], dh[2], dh[3]);       \
      *(uint4*)(basep + 8192) = make_uint4(dm[0], dm[1], dm[2], dm[3]);       \
    }                                                                         \
  } while (0)

#define CHUNK(c_, RB, WB, AC, AN) do {                                        \
    if ((c_) + 1 < NCHUNK) { LOAD_A(AN, (c_) + 1); LOAD_B((c_) + 1); }        \
    _Pragma("unroll")                                                         \
    for (int nb = 0; nb < 8; ++nb) {                                          \
      bf16x8 bH = *(const bf16x8*)((RB) + nb * 1024 + la16);                  \
      bf16x8 bM = *(const bf16x8*)((RB) + 8192 + nb * 1024 + la16);           \
      cip[nb] = __builtin_amdgcn_mfma_f32_16x16x32_bf16(AC[0], bH, cip[nb], 0, 0, 0); \
      cip[nb] = __builtin_amdgcn_mfma_f32_16x16x32_bf16(AC[0], bM, cip[nb], 0, 0, 0); \
      cip[nb] = __builtin_amdgcn_mfma_f32_16x16x32_bf16(AC[1], bH, cip[nb], 0, 0, 0); \
      cip[nb] = __builtin_amdgcn_mfma_f32_16x16x32_bf16(AC[1], bM, cip[nb], 0, 0, 0); \
      cip[nb] = __builtin_amdgcn_mfma_f32_16x16x32_bf16(AC[2], bH, cip[nb], 0, 0, 0); \
      cnp[nb] = __builtin_amdgcn_mfma_f32_16x16x32_bf16(AC[3], bH, cnp[nb], 0, 0, 0); \
      cnp[nb] = __builtin_amdgcn_mfma_f32_16x16x32_bf16(AC[3], bM, cnp[nb], 0, 0, 0); \
      cnp[nb] = __builtin_amdgcn_mfma_f32_16x16x32_bf16(AC[4], bH, cnp[nb], 0, 0, 0); \
    }                                                                         \
    if ((c_) + 1 < NCHUNK) WRITE_B(WB);                                       \
    __syncthreads();                                                          \
  } while (0)

  // prologue: chunk 0 staged into buf0
  LOAD_A(A0, 0);
  LOAD_B(0);
  WRITE_B(buf0);
  __syncthreads();

  #pragma unroll 1
  for (int cc = 0; cc < NCHUNK; cc += 2) {
    CHUNK(cc, buf0, buf1, A0, A1);
    CHUNK(cc + 1, buf1, buf0, A1, A0);
  }

  // ---------------- epilogue ----------------
  float* pvv  = (float*)ldsmem;           // [4][128]
  int*   pvi  = (int*)(ldsmem + 2048);
  float* pnm  = (float*)(ldsmem + 4096);
  float* pns  = (float*)(ldsmem + 6144);
  float* m2   = (float*)(ldsmem + 8192);  // [128]
  float* hbuf = (float*)(ldsmem + 8704);
  float* cbuf = (float*)(ldsmem + 9216);

  const size_t bn = (size_t)b * NCLS;
  float* ipo = out + IPOFF;
  const int rbase = 16 * w + ((l >> 4) & 3) * 4;
  const int c15 = l & 15;

  float bv[8]; int bi[8]; float nm[8];
  #pragma unroll
  for (int nb = 0; nb < 8; ++nb) {
    const int hw = hw0 + nb * 16 + c15;
    float best = -1e30f; int besti = 0;
    #pragma unroll
    for (int r = 0; r < 4; ++r) {
      const int n = rbase + r;
      const float v = cip[nb][r];
      ipo[(bn + n) * HWDIM + hw] = v;
      const float t = v + gumbel[(bn + n) * HWDIM + hw];
      if (t > best) { best = t; besti = n; }
    }
    bv[nb] = best; bi[nb] = besti;
    float m = cnp[nb][0];
    m = fmaxf(m, cnp[nb][1]); m = fmaxf(m, cnp[nb][2]); m = fmaxf(m, cnp[nb][3]);
    nm[nb] = m;
  }
  #pragma unroll
  for (int nb = 0; nb < 8; ++nb) {
    #pragma unroll
    for (int mk = 16; mk <= 32; mk <<= 1) {
      float ov = __shfl_xor(bv[nb], mk);
      int   oi = __shfl_xor(bi[nb], mk);
      if (ov > bv[nb] || (ov == bv[nb] && oi < bi[nb])) { bv[nb] = ov; bi[nb] = oi; }
      nm[nb] = fmaxf(nm[nb], __shfl_xor(nm[nb], mk));
    }
  }
  __syncthreads();   // LDS reuse: K-loop reads done before overwrite
  if ((l >> 4) == 0) {
    #pragma unroll
    for (int nb = 0; nb < 8; ++nb) {
      pvv[w * 128 + nb * 16 + l] = bv[nb];
      pvi[w * 128 + nb * 16 + l] = bi[nb];
      pnm[w * 128 + nb * 16 + l] = nm[nb];
    }
  }
  __syncthreads();

  if (tid < 128) {
    float v = pvv[tid]; int i = pvi[tid];
    #pragma unroll
    for (int ww = 1; ww < 4; ++ww) {
      float v2 = pvv[ww * 128 + tid]; int i2 = pvi[ww * 128 + tid];
      if (v2 > v || (v2 == v && i2 < i)) { v = v2; i = i2; }
    }
    float h = s_sh[i];
    hbuf[tid] = h;
    out[(size_t)b * HWDIM + hw0 + tid] = h;
    float m = pnm[tid];
    #pragma unroll
    for (int ww = 1; ww < 4; ++ww) m = fmaxf(m, pnm[ww * 128 + tid]);
    m2[tid] = m;
  }
  __syncthreads();

  #pragma unroll
  for (int nb = 0; nb < 8; ++nb) {
    const float mm = m2[nb * 16 + c15];
    float s = __expf(cnp[nb][0] - mm) + __expf(cnp[nb][1] - mm)
            + __expf(cnp[nb][2] - mm) + __expf(cnp[nb][3] - mm);
    s += __shfl_xor(s, 16);
    s += __shfl_xor(s, 32);
    if ((l >> 4) == 0) pns[w * 128 + nb * 16 + l] = s;
  }
  __syncthreads();

  if (tid < 128) {
    float S = pns[tid] + pns[128 + tid] + pns[256 + tid] + pns[384 + tid];
    cbuf[tid] = 1.0f / S;
  }
  __syncthreads();

  if (tid < 64) {
    float hs = hbuf[tid] + hbuf[tid + 64];
    float cs = cbuf[tid] + cbuf[tid + 64];
    #pragma unroll
    for (int o = 32; o > 0; o >>= 1) {
      hs += __shfl_down(hs, o);
      cs += __shfl_down(cs, o);
    }
    if (tid == 0) {
      ws[WS_PH + b * NTILES + tile] = hs;
      ws[WS_PC + b * NTILES + tile] = cs;
    }
  }
#undef LOAD_A
#undef LOAD_B
#undef WRITE_B
#undef CHUNK
}

// ---------------------------------------------------------------------------
// Finish: logits + cluster_loss from per-block partials (deterministic order)
// ---------------------------------------------------------------------------
__global__ __launch_bounds__(256) void finish_kernel(
    const float* __restrict__ ws, float* __restrict__ out) {
  __shared__ double sred[256];
  const int tid = threadIdx.x;
  {
    int bb = tid >> 4, lane = tid & 15;
    double s = 0.0;
    for (int t = lane; t < NTILES; t += 16) s += (double)ws[WS_PH + bb * NTILES + t];
    #pragma unroll
    for (int o = 8; o > 0; o >>= 1) s += __shfl_down(s, o, 16);
    if (lane == 0) out[LOGOFF + bb] = (float)(s / (double)HWDIM);
  }
  double c = 0.0;
  for (int i = tid; i < BATCH * NTILES; i += 256) c += (double)ws[WS_PC + i];
  sred[tid] = c;
  __syncthreads();
  for (int st = 128; st > 0; st >>= 1) {
    if (tid < st) sred[tid] += sred[tid + st];
    __syncthreads();
  }
  if (tid == 0) out[LOSSOFF] = (float)(-sred[0] / (double)(BATCH * HWDIM));
}

// ---------------------------------------------------------------------------
extern "C" void kernel_launch(void* const* d_in, const int* in_sizes, int n_in,
                              void* d_out, int out_size, void* d_ws, size_t ws_size,
                              hipStream_t stream) {
  const float* x       = (const float*)d_in[0];
  const float* centers = (const float*)d_in[1];
  const float* Aadj    = (const float*)d_in[2];
  const float* gumbel  = (const float*)d_in[3];
  const float* W_bc    = (const float*)d_in[4];
  const float* b_bc    = (const float*)d_in[5];
  const float* W_gcn   = (const float*)d_in[6];
  const float* b_gcn   = (const float*)d_in[7];
  float* out = (float*)d_out;
  float* ws  = (float*)d_ws;

  hipLaunchKernelGGL(prep_kernel, dim3(NCLS), dim3(256), 0, stream,
                     centers, Aadj, W_bc, b_bc, W_gcn, b_gcn, ws);
  hipLaunchKernelGGL(main_kernel, dim3(NTILES, BATCH), dim3(256), 0, stream,
                     x, gumbel, ws, out);
  hipLaunchKernelGGL(finish_kernel, dim3(1), dim3(256), 0, stream, ws, out);
}

// Round 14
// 186.392 us; speedup vs baseline: 1.3079x; 1.0008x over previous
//
#include <hip/hip_runtime.h>
#include <math.h>

// Problem constants
#define BATCH   16
#define CDIM    512
#define HWDIM   9216      // 96*96
#define NCLS    64
#define TILE    128
#define NTILES  72        // 9216/128
#define NCHUNK  16        // 512/32

// Output layout (floats): heatmap[16*9216], logits[16], loss[1], ip[16*64*9216]
#define LOGOFF  147456
#define LOSSOFF 147472
#define IPOFF   147473

// Workspace layout (floats)
#define WS_S    65536     // s[64]
#define WS_PH   65600     // per-block heat sums [1152]
#define WS_PC   66752     // per-block cluster sums [1152]
#define WS_AP   67904     // A-piece fragments: 16 chunks * 3p * 8mb * 64lane * 4 floats

typedef __attribute__((ext_vector_type(8))) short bf16x8;
typedef __attribute__((ext_vector_type(4))) float f32x4;

__device__ __forceinline__ void split3(float v, float& h, float& m, float& l) {
  float hf = __uint_as_float(__float_as_uint(v) & 0xFFFF0000u);
  float r  = v - hf;                    // exact
  float mf = __uint_as_float(__float_as_uint(r) & 0xFFFF0000u);
  float r2 = r - mf;                    // exact
  float lf = __uint_as_float(__float_as_uint(r2) & 0xFFFF0000u);
  h = hf; m = mf; l = lf;
}

__device__ __forceinline__ void split2(float v, float& h, float& m) {
  float hf = __uint_as_float(__float_as_uint(v) & 0xFFFF0000u);
  float r  = v - hf;                    // exact
  float mf = __uint_as_float(__float_as_uint(r) & 0xFFFF0000u);
  h = hf; m = mf;
}

__device__ __forceinline__ unsigned packbf(float a, float b) {
  return (__float_as_uint(a) >> 16) | (__float_as_uint(b) & 0xFFFF0000u);
}

// ---------------------------------------------------------------------------
// prep: block n (64 blocks) computes mix row n, s[n], new_centers row 64+n,
// and packs fragment rows n (centers) and 64+n (new_centers). (R11 verbatim)
// ---------------------------------------------------------------------------
__global__ __launch_bounds__(256) void prep_kernel(
    const float* __restrict__ centers, const float* __restrict__ Aadj,
    const float* __restrict__ W_bc, const float* __restrict__ b_bc,
    const float* __restrict__ W_gcn, const float* __restrict__ b_gcn,
    float* __restrict__ ws) {
  __shared__ float c_row[CDIM];
  __shared__ float mix_row[CDIM];
  __shared__ float new_row[CDIM];
  __shared__ float a_n[NCLS];
  __shared__ float red[256];
  const int n = blockIdx.x;
  const int tid = threadIdx.x;

  if (tid < NCLS) a_n[tid] = Aadj[n * NCLS + tid] + (tid == n ? 1.0f : 0.0f);
  __syncthreads();
  if (tid == 0) {
    float ssum = 0.f;
    for (int w = 0; w < NCLS; ++w) ssum += a_n[w];
    red[0] = 1.0f / ssum;
  }
  __syncthreads();
  float inv = red[0];
  __syncthreads();
  if (tid < NCLS) a_n[tid] *= inv;
  __syncthreads();

  float p = 0.f;
  for (int c = tid; c < CDIM; c += 256) {
    float v = centers[n * CDIM + c];
    c_row[c] = v;
    float acc = 0.f;
    #pragma unroll 8
    for (int w = 0; w < NCLS; ++w) acc = fmaf(a_n[w], centers[w * CDIM + c], acc);
    mix_row[c] = 0.05f * v + 0.95f * acc;
    p = fmaf(W_bc[c], v, p);
  }
  red[tid] = p;
  __syncthreads();
  for (int st = 128; st > 0; st >>= 1) {
    if (tid < st) red[tid] += red[tid + st];
    __syncthreads();
  }
  if (tid == 0) ws[WS_S + n] = red[0] + b_bc[0];
  __syncthreads();

  for (int o = tid; o < CDIM; o += 256) {
    const float4* wr0 = (const float4*)(W_gcn + (size_t)o * 1024);
    const float4* wr1 = (const float4*)(W_gcn + (size_t)o * 1024 + 512);
    const float4* cr4 = (const float4*)c_row;
    const float4* mr4 = (const float4*)mix_row;
    float a0 = b_gcn[o], a1 = 0.f, a2 = 0.f, a3 = 0.f;
    #pragma unroll 4
    for (int qk = 0; qk < 128; ++qk) {
      float4 wv = wr0[qk], cv = cr4[qk];
      a0 = fmaf(wv.x, cv.x, a0);
      a1 = fmaf(wv.y, cv.y, a1);
      a2 = fmaf(wv.z, cv.z, a2);
      a3 = fmaf(wv.w, cv.w, a3);
    }
    #pragma unroll 4
    for (int qk = 0; qk < 128; ++qk) {
      float4 wv = wr1[qk], mv = mr4[qk];
      a0 = fmaf(wv.x, mv.x, a0);
      a1 = fmaf(wv.y, mv.y, a1);
      a2 = fmaf(wv.z, mv.z, a2);
      a3 = fmaf(wv.w, mv.w, a3);
    }
    new_row[o] = (a0 + a1) + (a2 + a3);
  }
  __syncthreads();

  if (tid < 128) {
    const int rowsel = tid >> 6;          // 0: centers row, 1: new row
    const int u = tid & 63;
    const int c = u >> 2, q = u & 3;
    const float* rbuf = rowsel ? new_row : c_row;
    const int mb = (rowsel ? 4 : 0) + (n >> 4);
    const int lane = q * 16 + (n & 15);
    float e[8];
    #pragma unroll
    for (int i = 0; i < 8; ++i) e[i] = rbuf[c * 32 + q * 8 + i];
    unsigned dh[4], dm[4], dl[4];
    #pragma unroll
    for (int d = 0; d < 4; ++d) {
      float h0, m0, l0, h1, m1, l1;
      split3(e[2 * d], h0, m0, l0);
      split3(e[2 * d + 1], h1, m1, l1);
      dh[d] = packbf(h0, h1); dm[d] = packbf(m0, m1); dl[d] = packbf(l0, l1);
    }
    float* dst = ws + WS_AP + (size_t)c * 6144 + (size_t)mb * 256 + (size_t)lane * 4;
    *(uint4*)(dst)        = make_uint4(dh[0], dh[1], dh[2], dh[3]);
    *(uint4*)(dst + 2048) = make_uint4(dm[0], dm[1], dm[2], dm[3]);
    *(uint4*)(dst + 4096) = make_uint4(dl[0], dl[1], dl[2], dl[3]);
  }
}

// ---------------------------------------------------------------------------
// Main: MFMA split-bf16 dual GEMM (R11 skeleton) with 2-piece B staging:
// ip = aH*bH + aH*bM + aM*bH + aM*bM + aL*bH  (error ~2^-16 rel, negligible)
// nip = nH*bH + nH*bM + nM*bH
// B buffers use 2x16KB of a 49KB LDS block: LDS is deliberately held at R11's
// size so residency stays 3 blocks/CU (R13's 32KB -> 4 blocks/CU regressed).
// ---------------------------------------------------------------------------
__global__ __launch_bounds__(256, 3) void main_kernel(
    const float* __restrict__ x, const float* __restrict__ gumbel,
    float* __restrict__ ws, float* __restrict__ out) {
  __shared__ char ldsmem[49152];          // only first 32KB used for staging
  __shared__ float s_sh[NCLS];
  char* buf0 = ldsmem;
  char* buf1 = ldsmem + 16384;

  const int tid = threadIdx.x;
  const int w = tid >> 6, l = tid & 63;
  const int tile = blockIdx.x, b = blockIdx.y;
  const int hw0 = tile * TILE;

  if (tid < NCLS) s_sh[tid] = ws[WS_S + tid];
  // touch the upper 16KB so the compiler cannot shrink the LDS block
  if (tid == 0) ((volatile char*)ldsmem)[49151] = 0;

  const float* xb = x + (size_t)b * CDIM * HWDIM;
  const float* pB = xb + (size_t)(w * 8) * HWDIM + hw0 + l;   // k = c*32 + w*8 + j
  const char* ap = (const char*)(ws + WS_AP);
  const int la16 = l * 16;

  f32x4 cip[8], cnp[8];
  #pragma unroll
  for (int i = 0; i < 8; ++i) {
    cip[i] = (f32x4){0.f, 0.f, 0.f, 0.f};
    cnp[i] = (f32x4){0.f, 0.f, 0.f, 0.f};
  }

  float bre[16];
  bf16x8 A0[5], A1[5];

#define LOAD_A(AS, c_) do {                                                   \
    const char* asrc = ap + (size_t)(c_) * 24576;                             \
    AS[0] = *(const bf16x8*)(asrc + w * 1024 + la16);                         \
    AS[1] = *(const bf16x8*)(asrc + 8192 + w * 1024 + la16);                  \
    AS[2] = *(const bf16x8*)(asrc + 16384 + w * 1024 + la16);                 \
    AS[3] = *(const bf16x8*)(asrc + (4 + w) * 1024 + la16);                   \
    AS[4] = *(const bf16x8*)(asrc + 8192 + (4 + w) * 1024 + la16);            \
  } while (0)

#define LOAD_B(c_) do {                                                       \
    const size_t koff = (size_t)(c_) * 32 * HWDIM;                            \
    _Pragma("unroll")                                                         \
    for (int j = 0; j < 8; ++j) {                                             \
      bre[j]     = pB[koff + (size_t)j * HWDIM];                              \
      bre[8 + j] = pB[koff + (size_t)j * HWDIM + 64];                         \
    }                                                                         \
  } while (0)

#define WRITE_B(WB) do {                                                      \
    _Pragma("unroll")                                                         \
    for (int hh = 0; hh < 2; ++hh) {                                          \
      unsigned dh[4], dm[4];                                                  \
      _Pragma("unroll")                                                       \
      for (int d = 0; d < 4; ++d) {                                           \
        float h0, m0, h1, m1;                                                 \
        split2(bre[hh * 8 + 2 * d], h0, m0);                                  \
        split2(bre[hh * 8 + 2 * d + 1], h1, m1);                              \
        dh[d] = packbf(h0, h1); dm[d] = packbf(m0, m1);                       \
      }                                                                       \
      char* basep = (WB) + ((((l >> 4) + hh * 4) * 64) + (w << 4) + (l & 15)) * 16; \
      *(uint4*)(basep)        = make_uint4(dh[0], dh[1], dh[2], dh[3]);       \
      *(uint4*)(basep + 8192) = make_uint4(dm[0], dm[1], dm[2], dm[3]);       \
    }                                                                         \
  } while (0)

#define CHUNK(c_, RB, WB, AC, AN) do {                                        \
    if ((c_) + 1 < NCHUNK) { LOAD_A(AN, (c_) + 1); LOAD_B((c_) + 1); }        \
    _Pragma("unroll")                                                         \
    for (int nb = 0; nb < 8; ++nb) {                                          \
      bf16x8 bH = *(const bf16x8*)((RB) + nb * 1024 + la16);                  \
      bf16x8 bM = *(const bf16x8*)((RB) + 8192 + nb * 1024 + la16);           \
      cip[nb] = __builtin_amdgcn_mfma_f32_16x16x32_bf16(AC[0], bH, cip[nb], 0, 0, 0); \
      cip[nb] = __builtin_amdgcn_mfma_f32_16x16x32_bf16(AC[0], bM, cip[nb], 0, 0, 0); \
      cip[nb] = __builtin_amdgcn_mfma_f32_16x16x32_bf16(AC[1], bH, cip[nb], 0, 0, 0); \
      cip[nb] = __builtin_amdgcn_mfma_f32_16x16x32_bf16(AC[1], bM, cip[nb], 0, 0, 0); \
      cip[nb] = __builtin_amdgcn_mfma_f32_16x16x32_bf16(AC[2], bH, cip[nb], 0, 0, 0); \
      cnp[nb] = __builtin_amdgcn_mfma_f32_16x16x32_bf16(AC[3], bH, cnp[nb], 0, 0, 0); \
      cnp[nb] = __builtin_amdgcn_mfma_f32_16x16x32_bf16(AC[3], bM, cnp[nb], 0, 0, 0); \
      cnp[nb] = __builtin_amdgcn_mfma_f32_16x16x32_bf16(AC[4], bH, cnp[nb], 0, 0, 0); \
    }                                                                         \
    if ((c_) + 1 < NCHUNK) WRITE_B(WB);                                       \
    __syncthreads();                                                          \
  } while (0)

  // prologue: chunk 0 staged into buf0
  LOAD_A(A0, 0);
  LOAD_B(0);
  WRITE_B(buf0);
  __syncthreads();

  #pragma unroll 1
  for (int cc = 0; cc < NCHUNK; cc += 2) {
    CHUNK(cc, buf0, buf1, A0, A1);
    CHUNK(cc + 1, buf1, buf0, A1, A0);
  }

  // ---------------- epilogue ----------------
  float* pvv  = (float*)ldsmem;           // [4][128]
  int*   pvi  = (int*)(ldsmem + 2048);
  float* pnm  = (float*)(ldsmem + 4096);
  float* pns  = (float*)(ldsmem + 6144);
  float* m2   = (float*)(ldsmem + 8192);  // [128]
  float* hbuf = (float*)(ldsmem + 8704);
  float* cbuf = (float*)(ldsmem + 9216);

  const size_t bn = (size_t)b * NCLS;
  float* ipo = out + IPOFF;
  const int rbase = 16 * w + ((l >> 4) & 3) * 4;
  const int c15 = l & 15;

  float bv[8]; int bi[8]; float nm[8];
  #pragma unroll
  for (int nb = 0; nb < 8; ++nb) {
    const int hw = hw0 + nb * 16 + c15;
    float best = -1e30f; int besti = 0;
    #pragma unroll
    for (int r = 0; r < 4; ++r) {
      const int n = rbase + r;
      const float v = cip[nb][r];
      ipo[(bn + n) * HWDIM + hw] = v;
      const float t = v + gumbel[(bn + n) * HWDIM + hw];
      if (t > best) { best = t; besti = n; }
    }
    bv[nb] = best; bi[nb] = besti;
    float m = cnp[nb][0];
    m = fmaxf(m, cnp[nb][1]); m = fmaxf(m, cnp[nb][2]); m = fmaxf(m, cnp[nb][3]);
    nm[nb] = m;
  }
  #pragma unroll
  for (int nb = 0; nb < 8; ++nb) {
    #pragma unroll
    for (int mk = 16; mk <= 32; mk <<= 1) {
      float ov = __shfl_xor(bv[nb], mk);
      int   oi = __shfl_xor(bi[nb], mk);
      if (ov > bv[nb] || (ov == bv[nb] && oi < bi[nb])) { bv[nb] = ov; bi[nb] = oi; }
      nm[nb] = fmaxf(nm[nb], __shfl_xor(nm[nb], mk));
    }
  }
  __syncthreads();   // LDS reuse: K-loop reads done before overwrite
  if ((l >> 4) == 0) {
    #pragma unroll
    for (int nb = 0; nb < 8; ++nb) {
      pvv[w * 128 + nb * 16 + l] = bv[nb];
      pvi[w * 128 + nb * 16 + l] = bi[nb];
      pnm[w * 128 + nb * 16 + l] = nm[nb];
    }
  }
  __syncthreads();

  if (tid < 128) {
    float v = pvv[tid]; int i = pvi[tid];
    #pragma unroll
    for (int ww = 1; ww < 4; ++ww) {
      float v2 = pvv[ww * 128 + tid]; int i2 = pvi[ww * 128 + tid];
      if (v2 > v || (v2 == v && i2 < i)) { v = v2; i = i2; }
    }
    float h = s_sh[i];
    hbuf[tid] = h;
    out[(size_t)b * HWDIM + hw0 + tid] = h;
    float m = pnm[tid];
    #pragma unroll
    for (int ww = 1; ww < 4; ++ww) m = fmaxf(m, pnm[ww * 128 + tid]);
    m2[tid] = m;
  }
  __syncthreads();

  #pragma unroll
  for (int nb = 0; nb < 8; ++nb) {
    const float mm = m2[nb * 16 + c15];
    float s = __expf(cnp[nb][0] - mm) + __expf(cnp[nb][1] - mm)
            + __expf(cnp[nb][2] - mm) + __expf(cnp[nb][3] - mm);
    s += __shfl_xor(s, 16);
    s += __shfl_xor(s, 32);
    if ((l >> 4) == 0) pns[w * 128 + nb * 16 + l] = s;
  }
  __syncthreads();

  if (tid < 128) {
    float S = pns[tid] + pns[128 + tid] + pns[256 + tid] + pns[384 + tid];
    cbuf[tid] = 1.0f / S;
  }
  __syncthreads();

  if (tid < 64) {
    float hs = hbuf[tid] + hbuf[tid + 64];
    float cs = cbuf[tid] + cbuf[tid + 64];
    #pragma unroll
    for (int o = 32; o > 0; o >>= 1) {
      hs += __shfl_down(hs, o);
      cs += __shfl_down(cs, o);
    }
    if (tid == 0) {
      ws[WS_PH + b * NTILES + tile] = hs;
      ws[WS_PC + b * NTILES + tile] = cs;
    }
  }
#undef LOAD_A
#undef LOAD_B
#undef WRITE_B
#undef CHUNK
}

// ---------------------------------------------------------------------------
// Finish: logits + cluster_loss from per-block partials (deterministic order)
// ---------------------------------------------------------------------------
__global__ __launch_bounds__(256) void finish_kernel(
    const float* __restrict__ ws, float* __restrict__ out) {
  __shared__ double sred[256];
  const int tid = threadIdx.x;
  {
    int bb = tid >> 4, lane = tid & 15;
    double s = 0.0;
    for (int t = lane; t < NTILES; t += 16) s += (double)ws[WS_PH + bb * NTILES + t];
    #pragma unroll
    for (int o = 8; o > 0; o >>= 1) s += __shfl_down(s, o, 16);
    if (lane == 0) out[LOGOFF + bb] = (float)(s / (double)HWDIM);
  }
  double c = 0.0;
  for (int i = tid; i < BATCH * NTILES; i += 256) c += (double)ws[WS_PC + i];
  sred[tid] = c;
  __syncthreads();
  for (int st = 128; st > 0; st >>= 1) {
    if (tid < st) sred[tid] += sred[tid + st];
    __syncthreads();
  }
  if (tid == 0) out[LOSSOFF] = (float)(-sred[0] / (double)(BATCH * HWDIM));
}

// ---------------------------------------------------------------------------
extern "C" void kernel_launch(void* const* d_in, const int* in_sizes, int n_in,
                              void* d_out, int out_size, void* d_ws, size_t ws_size,
                              hipStream_t stream) {
  const float* x       = (const float*)d_in[0];
  const float* centers = (const float*)d_in[1];
  const float* Aadj    = (const float*)d_in[2];
  const float* gumbel  = (const float*)d_in[3];
  const float* W_bc    = (const float*)d_in[4];
  const float* b_bc    = (const float*)d_in[5];
  const float* W_gcn   = (const float*)d_in[6];
  const float* b_gcn   = (const float*)d_in[7];
  float* out = (float*)d_out;
  float* ws  = (float*)d_ws;

  hipLaunchKernelGGL(prep_kernel, dim3(NCLS), dim3(256), 0, stream,
                     centers, Aadj, W_bc, b_bc, W_gcn, b_gcn, ws);
  hipLaunchKernelGGL(main_kernel, dim3(NTILES, BATCH), dim3(256), 0, stream,
                     x, gumbel, ws, out);
  hipLaunchKernelGGL(finish_kernel, dim3(1), dim3(256), 0, stream, ws, out);
}

// Round 15
// 175.896 us; speedup vs baseline: 1.3859x; 1.0597x over previous
//
#include <hip/hip_runtime.h>
#include <math.h>

// Problem constants
#define BATCH   16
#define CDIM    512
#define HWDIM   9216      // 96*96
#define NCLS    64
#define TILE    128
#define NTILES  72        // 9216/128
#define NCHUNK  16        // 512/32

// Output layout (floats): heatmap[16*9216], logits[16], loss[1], ip[16*64*9216]
#define LOGOFF  147456
#define LOSSOFF 147472
#define IPOFF   147473

// Workspace layout (floats)
#define WS_S    65536     // s[64]
#define WS_PH   65600     // per-block heat sums [1152]
#define WS_PC   66752     // per-block cluster sums [1152]
#define WS_AP   67904     // A-piece fragments: 16 chunks * 3p * 8mb * 64lane * 4 floats

typedef __attribute__((ext_vector_type(8))) short bf16x8;
typedef __attribute__((ext_vector_type(4))) float f32x4;

__device__ __forceinline__ void split3(float v, float& h, float& m, float& l) {
  float hf = __uint_as_float(__float_as_uint(v) & 0xFFFF0000u);
  float r  = v - hf;                    // exact
  float mf = __uint_as_float(__float_as_uint(r) & 0xFFFF0000u);
  float r2 = r - mf;                    // exact
  float lf = __uint_as_float(__float_as_uint(r2) & 0xFFFF0000u);
  h = hf; m = mf; l = lf;
}

__device__ __forceinline__ unsigned packbf(float a, float b) {
  return (__float_as_uint(a) >> 16) | (__float_as_uint(b) & 0xFFFF0000u);
}

// ---------------------------------------------------------------------------
// prep: block n (64 blocks) computes mix row n, s[n], new_centers row 64+n,
// and packs fragment rows n (centers) and 64+n (new_centers).
// ---------------------------------------------------------------------------
__global__ __launch_bounds__(256) void prep_kernel(
    const float* __restrict__ centers, const float* __restrict__ Aadj,
    const float* __restrict__ W_bc, const float* __restrict__ b_bc,
    const float* __restrict__ W_gcn, const float* __restrict__ b_gcn,
    float* __restrict__ ws) {
  __shared__ float c_row[CDIM];
  __shared__ float mix_row[CDIM];
  __shared__ float new_row[CDIM];
  __shared__ float a_n[NCLS];
  __shared__ float red[256];
  const int n = blockIdx.x;
  const int tid = threadIdx.x;

  if (tid < NCLS) a_n[tid] = Aadj[n * NCLS + tid] + (tid == n ? 1.0f : 0.0f);
  __syncthreads();
  if (tid == 0) {
    float ssum = 0.f;
    for (int w = 0; w < NCLS; ++w) ssum += a_n[w];
    red[0] = 1.0f / ssum;
  }
  __syncthreads();
  float inv = red[0];
  __syncthreads();
  if (tid < NCLS) a_n[tid] *= inv;
  __syncthreads();

  // mix row n + s[n] partial
  float p = 0.f;
  for (int c = tid; c < CDIM; c += 256) {
    float v = centers[n * CDIM + c];
    c_row[c] = v;
    float acc = 0.f;
    #pragma unroll 8
    for (int w = 0; w < NCLS; ++w) acc = fmaf(a_n[w], centers[w * CDIM + c], acc);
    mix_row[c] = 0.05f * v + 0.95f * acc;
    p = fmaf(W_bc[c], v, p);
  }
  red[tid] = p;
  __syncthreads();
  for (int st = 128; st > 0; st >>= 1) {
    if (tid < st) red[tid] += red[tid + st];
    __syncthreads();
  }
  if (tid == 0) ws[WS_S + n] = red[0] + b_bc[0];
  __syncthreads();

  // new_centers row 64+n
  for (int o = tid; o < CDIM; o += 256) {
    const float4* wr0 = (const float4*)(W_gcn + (size_t)o * 1024);
    const float4* wr1 = (const float4*)(W_gcn + (size_t)o * 1024 + 512);
    const float4* cr4 = (const float4*)c_row;
    const float4* mr4 = (const float4*)mix_row;
    float a0 = b_gcn[o], a1 = 0.f, a2 = 0.f, a3 = 0.f;
    #pragma unroll 4
    for (int qk = 0; qk < 128; ++qk) {
      float4 wv = wr0[qk], cv = cr4[qk];
      a0 = fmaf(wv.x, cv.x, a0);
      a1 = fmaf(wv.y, cv.y, a1);
      a2 = fmaf(wv.z, cv.z, a2);
      a3 = fmaf(wv.w, cv.w, a3);
    }
    #pragma unroll 4
    for (int qk = 0; qk < 128; ++qk) {
      float4 wv = wr1[qk], mv = mr4[qk];
      a0 = fmaf(wv.x, mv.x, a0);
      a1 = fmaf(wv.y, mv.y, a1);
      a2 = fmaf(wv.z, mv.z, a2);
      a3 = fmaf(wv.w, mv.w, a3);
    }
    new_row[o] = (a0 + a1) + (a2 + a3);
  }
  __syncthreads();

  // pack rows n (c_row, mb=n>>4) and 64+n (new_row, mb=4+(n>>4))
  if (tid < 128) {
    const int rowsel = tid >> 6;          // 0: centers row, 1: new row
    const int u = tid & 63;
    const int c = u >> 2, q = u & 3;
    const float* rbuf = rowsel ? new_row : c_row;
    const int mb = (rowsel ? 4 : 0) + (n >> 4);
    const int lane = q * 16 + (n & 15);
    float e[8];
    #pragma unroll
    for (int i = 0; i < 8; ++i) e[i] = rbuf[c * 32 + q * 8 + i];
    unsigned dh[4], dm[4], dl[4];
    #pragma unroll
    for (int d = 0; d < 4; ++d) {
      float h0, m0, l0, h1, m1, l1;
      split3(e[2 * d], h0, m0, l0);
      split3(e[2 * d + 1], h1, m1, l1);
      dh[d] = packbf(h0, h1); dm[d] = packbf(m0, m1); dl[d] = packbf(l0, l1);
    }
    float* dst = ws + WS_AP + (size_t)c * 6144 + (size_t)mb * 256 + (size_t)lane * 4;
    *(uint4*)(dst)        = make_uint4(dh[0], dh[1], dh[2], dh[3]);
    *(uint4*)(dst + 2048) = make_uint4(dm[0], dm[1], dm[2], dm[3]);
    *(uint4*)(dst + 4096) = make_uint4(dl[0], dl[1], dl[2], dl[3]);
  }
}

// ---------------------------------------------------------------------------
// Main: MFMA split-bf16 dual GEMM (R3 skeleton, verbatim — best measured).
// 3-piece exact split; A register-prefetched 1 chunk ahead from L2; B
// reg-staged 1-chunk lead into double-buffered LDS; one barrier per chunk.
// ---------------------------------------------------------------------------
__global__ __launch_bounds__(256, 3) void main_kernel(
    const float* __restrict__ x, const float* __restrict__ gumbel,
    float* __restrict__ ws, float* __restrict__ out) {
  __shared__ char ldsmem[49152];          // 2 x 24576 B-piece buffers
  __shared__ float s_sh[NCLS];
  char* buf0 = ldsmem;
  char* buf1 = ldsmem + 24576;

  const int tid = threadIdx.x;
  const int w = tid >> 6, l = tid & 63;
  const int tile = blockIdx.x, b = blockIdx.y;
  const int hw0 = tile * TILE;

  if (tid < NCLS) s_sh[tid] = ws[WS_S + tid];

  const float* xb = x + (size_t)b * CDIM * HWDIM;
  const float* pB = xb + (size_t)(w * 8) * HWDIM + hw0 + l;   // k = c*32 + w*8 + j
  const char* ap = (const char*)(ws + WS_AP);
  const int la16 = l * 16;

  f32x4 cip[8], cnp[8];
  #pragma unroll
  for (int i = 0; i < 8; ++i) {
    cip[i] = (f32x4){0.f, 0.f, 0.f, 0.f};
    cnp[i] = (f32x4){0.f, 0.f, 0.f, 0.f};
  }

  float bre[16];
  bf16x8 A0[5], A1[5];

#define LOAD_A(AS, c_) do {                                                   \
    const char* asrc = ap + (size_t)(c_) * 24576;                             \
    AS[0] = *(const bf16x8*)(asrc + w * 1024 + la16);                         \
    AS[1] = *(const bf16x8*)(asrc + 8192 + w * 1024 + la16);                  \
    AS[2] = *(const bf16x8*)(asrc + 16384 + w * 1024 + la16);                 \
    AS[3] = *(const bf16x8*)(asrc + (4 + w) * 1024 + la16);                   \
    AS[4] = *(const bf16x8*)(asrc + 8192 + (4 + w) * 1024 + la16);            \
  } while (0)

#define LOAD_B(c_) do {                                                       \
    const size_t koff = (size_t)(c_) * 32 * HWDIM;                            \
    _Pragma("unroll")                                                         \
    for (int j = 0; j < 8; ++j) {                                             \
      bre[j]     = pB[koff + (size_t)j * HWDIM];                              \
      bre[8 + j] = pB[koff + (size_t)j * HWDIM + 64];                         \
    }                                                                         \
  } while (0)

#define WRITE_B(WB) do {                                                      \
    _Pragma("unroll")                                                         \
    for (int hh = 0; hh < 2; ++hh) {                                          \
      unsigned dh[4], dm[4], dl[4];                                           \
      _Pragma("unroll")                                                       \
      for (int d = 0; d < 4; ++d) {                                           \
        float h0, m0, l0, h1, m1, l1;                                         \
        split3(bre[hh * 8 + 2 * d], h0, m0, l0);                              \
        split3(bre[hh * 8 + 2 * d + 1], h1, m1, l1);                          \
        dh[d] = packbf(h0, h1); dm[d] = packbf(m0, m1); dl[d] = packbf(l0, l1);\
      }                                                                       \
      char* basep = (WB) + ((((l >> 4) + hh * 4) * 64) + (w << 4) + (l & 15)) * 16; \
      *(uint4*)(basep)         = make_uint4(dh[0], dh[1], dh[2], dh[3]);      \
      *(uint4*)(basep + 8192)  = make_uint4(dm[0], dm[1], dm[2], dm[3]);      \
      *(uint4*)(basep + 16384) = make_uint4(dl[0], dl[1], dl[2], dl[3]);      \
    }                                                                         \
  } while (0)

#define CHUNK(c_, RB, WB, AC, AN) do {                                        \
    if ((c_) + 1 < NCHUNK) { LOAD_A(AN, (c_) + 1); LOAD_B((c_) + 1); }        \
    _Pragma("unroll")                                                         \
    for (int nb = 0; nb < 8; ++nb) {                                          \
      bf16x8 bH = *(const bf16x8*)((RB) + nb * 1024 + la16);                  \
      bf16x8 bM = *(const bf16x8*)((RB) + 8192 + nb * 1024 + la16);           \
      bf16x8 bL = *(const bf16x8*)((RB) + 16384 + nb * 1024 + la16);          \
      cip[nb] = __builtin_amdgcn_mfma_f32_16x16x32_bf16(AC[0], bH, cip[nb], 0, 0, 0); \
      cip[nb] = __builtin_amdgcn_mfma_f32_16x16x32_bf16(AC[0], bM, cip[nb], 0, 0, 0); \
      cip[nb] = __builtin_amdgcn_mfma_f32_16x16x32_bf16(AC[1], bH, cip[nb], 0, 0, 0); \
      cip[nb] = __builtin_amdgcn_mfma_f32_16x16x32_bf16(AC[0], bL, cip[nb], 0, 0, 0); \
      cip[nb] = __builtin_amdgcn_mfma_f32_16x16x32_bf16(AC[1], bM, cip[nb], 0, 0, 0); \
      cip[nb] = __builtin_amdgcn_mfma_f32_16x16x32_bf16(AC[2], bH, cip[nb], 0, 0, 0); \
      cnp[nb] = __builtin_amdgcn_mfma_f32_16x16x32_bf16(AC[3], bH, cnp[nb], 0, 0, 0); \
      cnp[nb] = __builtin_amdgcn_mfma_f32_16x16x32_bf16(AC[3], bM, cnp[nb], 0, 0, 0); \
      cnp[nb] = __builtin_amdgcn_mfma_f32_16x16x32_bf16(AC[4], bH, cnp[nb], 0, 0, 0); \
    }                                                                         \
    if ((c_) + 1 < NCHUNK) WRITE_B(WB);                                       \
    __syncthreads();                                                          \
  } while (0)

  // prologue: chunk 0 staged into buf0
  LOAD_A(A0, 0);
  LOAD_B(0);
  WRITE_B(buf0);
  __syncthreads();

  #pragma unroll 1
  for (int cc = 0; cc < NCHUNK; cc += 2) {
    CHUNK(cc, buf0, buf1, A0, A1);
    CHUNK(cc + 1, buf1, buf0, A1, A0);
  }

  // ---------------- epilogue ----------------
  float* pvv  = (float*)ldsmem;           // [4][128]
  int*   pvi  = (int*)(ldsmem + 2048);
  float* pnm  = (float*)(ldsmem + 4096);
  float* pns  = (float*)(ldsmem + 6144);
  float* m2   = (float*)(ldsmem + 8192);  // [128]
  float* hbuf = (float*)(ldsmem + 8704);
  float* cbuf = (float*)(ldsmem + 9216);

  const size_t bn = (size_t)b * NCLS;
  float* ipo = out + IPOFF;
  const int rbase = 16 * w + ((l >> 4) & 3) * 4;
  const int c15 = l & 15;

  float bv[8]; int bi[8]; float nm[8];
  #pragma unroll
  for (int nb = 0; nb < 8; ++nb) {
    const int hw = hw0 + nb * 16 + c15;
    float best = -1e30f; int besti = 0;
    #pragma unroll
    for (int r = 0; r < 4; ++r) {
      const int n = rbase + r;
      const float v = cip[nb][r];
      ipo[(bn + n) * HWDIM + hw] = v;
      const float t = v + gumbel[(bn + n) * HWDIM + hw];
      if (t > best) { best = t; besti = n; }
    }
    bv[nb] = best; bi[nb] = besti;
    float m = cnp[nb][0];
    m = fmaxf(m, cnp[nb][1]); m = fmaxf(m, cnp[nb][2]); m = fmaxf(m, cnp[nb][3]);
    nm[nb] = m;
  }
  #pragma unroll
  for (int nb = 0; nb < 8; ++nb) {
    #pragma unroll
    for (int mk = 16; mk <= 32; mk <<= 1) {
      float ov = __shfl_xor(bv[nb], mk);
      int   oi = __shfl_xor(bi[nb], mk);
      if (ov > bv[nb] || (ov == bv[nb] && oi < bi[nb])) { bv[nb] = ov; bi[nb] = oi; }
      nm[nb] = fmaxf(nm[nb], __shfl_xor(nm[nb], mk));
    }
  }
  if ((l >> 4) == 0) {
    #pragma unroll
    for (int nb = 0; nb < 8; ++nb) {
      pvv[w * 128 + nb * 16 + l] = bv[nb];
      pvi[w * 128 + nb * 16 + l] = bi[nb];
      pnm[w * 128 + nb * 16 + l] = nm[nb];
    }
  }
  __syncthreads();

  if (tid < 128) {
    float v = pvv[tid]; int i = pvi[tid];
    #pragma unroll
    for (int ww = 1; ww < 4; ++ww) {
      float v2 = pvv[ww * 128 + tid]; int i2 = pvi[ww * 128 + tid];
      if (v2 > v || (v2 == v && i2 < i)) { v = v2; i = i2; }
    }
    float h = s_sh[i];
    hbuf[tid] = h;
    out[(size_t)b * HWDIM + hw0 + tid] = h;
    float m = pnm[tid];
    #pragma unroll
    for (int ww = 1; ww < 4; ++ww) m = fmaxf(m, pnm[ww * 128 + tid]);
    m2[tid] = m;
  }
  __syncthreads();

  #pragma unroll
  for (int nb = 0; nb < 8; ++nb) {
    const float mm = m2[nb * 16 + c15];
    float s = __expf(cnp[nb][0] - mm) + __expf(cnp[nb][1] - mm)
            + __expf(cnp[nb][2] - mm) + __expf(cnp[nb][3] - mm);
    s += __shfl_xor(s, 16);
    s += __shfl_xor(s, 32);
    if ((l >> 4) == 0) pns[w * 128 + nb * 16 + l] = s;
  }
  __syncthreads();

  if (tid < 128) {
    float S = pns[tid] + pns[128 + tid] + pns[256 + tid] + pns[384 + tid];
    cbuf[tid] = 1.0f / S;
  }
  __syncthreads();

  if (tid < 64) {
    float hs = hbuf[tid] + hbuf[tid + 64];
    float cs = cbuf[tid] + cbuf[tid + 64];
    #pragma unroll
    for (int o = 32; o > 0; o >>= 1) {
      hs += __shfl_down(hs, o);
      cs += __shfl_down(cs, o);
    }
    if (tid == 0) {
      ws[WS_PH + b * NTILES + tile] = hs;
      ws[WS_PC + b * NTILES + tile] = cs;
    }
  }
#undef LOAD_A
#undef LOAD_B
#undef WRITE_B
#undef CHUNK
}

// ---------------------------------------------------------------------------
// Finish: logits + cluster_loss from per-block partials (deterministic order)
// ---------------------------------------------------------------------------
__global__ __launch_bounds__(256) void finish_kernel(
    const float* __restrict__ ws, float* __restrict__ out) {
  __shared__ double sred[256];
  const int tid = threadIdx.x;
  {
    int bb = tid >> 4, lane = tid & 15;
    double s = 0.0;
    for (int t = lane; t < NTILES; t += 16) s += (double)ws[WS_PH + bb * NTILES + t];
    #pragma unroll
    for (int o = 8; o > 0; o >>= 1) s += __shfl_down(s, o, 16);
    if (lane == 0) out[LOGOFF + bb] = (float)(s / (double)HWDIM);
  }
  double c = 0.0;
  for (int i = tid; i < BATCH * NTILES; i += 256) c += (double)ws[WS_PC + i];
  sred[tid] = c;
  __syncthreads();
  for (int st = 128; st > 0; st >>= 1) {
    if (tid < st) sred[tid] += sred[tid + st];
    __syncthreads();
  }
  if (tid == 0) out[LOSSOFF] = (float)(-sred[0] / (double)(BATCH * HWDIM));
}

// ---------------------------------------------------------------------------
extern "C" void kernel_launch(void* const* d_in, const int* in_sizes, int n_in,
                              void* d_out, int out_size, void* d_ws, size_t ws_size,
                              hipStream_t stream) {
  const float* x       = (const float*)d_in[0];
  const float* centers = (const float*)d_in[1];
  const float* Aadj    = (const float*)d_in[2];
  const float* gumbel  = (const float*)d_in[3];
  const float* W_bc    = (const float*)d_in[4];
  const float* b_bc    = (const float*)d_in[5];
  const float* W_gcn   = (const float*)d_in[6];
  const float* b_gcn   = (const float*)d_in[7];
  float* out = (float*)d_out;
  float* ws  = (float*)d_ws;

  hipLaunchKernelGGL(prep_kernel, dim3(NCLS), dim3(256), 0, stream,
                     centers, Aadj, W_bc, b_bc, W_gcn, b_gcn, ws);
  hipLaunchKernelGGL(main_kernel, dim3(NTILES, BATCH), dim3(256), 0, stream,
                     x, gumbel, ws, out);
  hipLaunchKernelGGL(finish_kernel, dim3(1), dim3(256), 0, stream, ws, out);
}